// Round 4
// baseline (1272.610 us; speedup 1.0000x reference)
//
#include <hip/hip_runtime.h>
#include <hip/hip_bf16.h>
#include <cstdint>

// Problem constants (from reference)
#define TT     2048   // tokens
#define KSEL   6      // experts per token
#define DMODEL 2048   // model dim
#define DINTER 1408   // moe intermediate dim
#define NE     16     // routed experts
#define PMAX   (TT * KSEL)

typedef short bf16x8 __attribute__((ext_vector_type(8)));
typedef float f32x4 __attribute__((ext_vector_type(4)));
typedef unsigned short u16;
typedef u16 u16x8 __attribute__((ext_vector_type(8)));

__device__ __forceinline__ u16 f2bf(float f) {
  union { float f; unsigned u; } v; v.f = f;
  return (u16)((v.u + 0x7FFFu + ((v.u >> 16) & 1u)) >> 16);  // RNE
}

__device__ __forceinline__ void gl2lds16(const void* g, void* l) {
  __builtin_amdgcn_global_load_lds((const __attribute__((address_space(1))) void*)g,
                                   (__attribute__((address_space(3))) void*)l,
                                   16, 0, 0);
}

// boundary waits: allow N loads (the freshly-issued t+2 stage) to remain in flight
#define VMCNT_BAR(N) do { \
  asm volatile("s_waitcnt vmcnt(" #N ")" ::: "memory"); \
  __builtin_amdgcn_s_barrier(); \
} while (0)

// gate_w[t,e] = sum_k weights[t,k]*(indices[t,k]==e); count routed (t,e) pairs
__global__ void k_gate(const float* __restrict__ w, const int* __restrict__ idx,
                       float* __restrict__ gate_w, int* __restrict__ counts) {
  int g = blockIdx.x * 256 + threadIdx.x;  // T*E threads
  int t = g >> 4, e = g & 15;
  const int* ip = idx + t * KSEL;
  const float* wp = w + t * KSEL;
  float s = 0.f;
#pragma unroll
  for (int k = 0; k < KSEL; ++k) s += (ip[k] == e) ? wp[k] : 0.f;
  gate_w[g] = s;
  if (s != 0.f) atomicAdd(counts + e, 1);
}

__global__ void k_scan(const int* __restrict__ counts, int* __restrict__ offs) {
  if (threadIdx.x == 0 && blockIdx.x == 0) {
    int r = 0;
#pragma unroll
    for (int e = 0; e < NE; ++e) { offs[e] = r; r += counts[e]; }
    offs[NE] = r;
  }
}

__global__ void k_fill(const float* __restrict__ gate_w, const int* __restrict__ offs,
                       int* __restrict__ cursor, int* __restrict__ slot_tok,
                       float* __restrict__ slot_gate) {
  int g = blockIdx.x * 256 + threadIdx.x;
  int t = g >> 4, e = g & 15;
  float s = gate_w[g];
  if (s != 0.f) {
    int p = atomicAdd(cursor + e, 1);
    int sl = offs[e] + p;
    slot_tok[sl] = t;
    slot_gate[sl] = s;
  }
}

// grid-strided fp32 -> bf16 cast, 8 elems/thread
__global__ void k_castw(const float* __restrict__ src, u16* __restrict__ dst, int n8) {
  int stride = gridDim.x * 256;
  for (int i = blockIdx.x * 256 + threadIdx.x; i < n8; i += stride) {
    const float4* p = (const float4*)src + (size_t)i * 2;
    float4 v0 = p[0], v1 = p[1];
    u16x8 o;
    o[0] = f2bf(v0.x); o[1] = f2bf(v0.y); o[2] = f2bf(v0.z); o[3] = f2bf(v0.w);
    o[4] = f2bf(v1.x); o[5] = f2bf(v1.y); o[6] = f2bf(v1.z); o[7] = f2bf(v1.w);
    *(u16x8*)(dst + (size_t)i * 8) = o;
  }
}

// GEMM1: act[slot, i] = silu(x@WgT)*(x@WuT)*gate, per expert token-group.
// 256(M) x 128(N inter) tile, BK=32, 8 waves (4Mx2N, 64x64 dual-acc).
// TRIPLE-buffered K-tiles: stage(t+2) during compute(t); boundary = vmcnt(4)+barrier.
// Race-free by rotation: buf b (=t%3) is next written by tile t+3, whose stage is
// issued during compute(t+1), i.e. strictly after the t->t+1 barrier ended all
// reads of b. vmcnt(4) leaves only t+2's 4 loads in flight => t+1 fully landed.
__global__ __launch_bounds__(512, 2) void k_gemm1(
    const u16* __restrict__ xb, const u16* __restrict__ wgb, const u16* __restrict__ wub,
    const int* __restrict__ slot_tok, const float* __restrict__ slot_gate,
    const int* __restrict__ offs, const int* __restrict__ counts,
    u16* __restrict__ act) {
  // grid flat = 8(mt) x 11(it) x 16(e) = 1408 = 8*176; XCD-chunked swizzle
  int b = blockIdx.x;
  int w = (b & 7) * 176 + (b >> 3);
  int mt = w & 7, rest = w >> 3;
  int it = rest % 11, e = rest / 11;

  int mcount = counts[e];
  if (mt * 256 >= mcount) return;
  int mrem = mcount - mt * 256; if (mrem > 256) mrem = 256;
  int slotBase = offs[e] + mt * 256;
  int iBase = it * 128;

  __shared__ u16 sA[3][256 * 32];   // 16 KB per buffer
  __shared__ u16 sG[3][128 * 32];   // 8 KB per buffer
  __shared__ u16 sU[3][128 * 32];   // 8 KB per buffer  -> 96 KB total
  __shared__ int tokLds[256];
  __shared__ float gateLds[256];

  int tid = threadIdx.x;
  if (tid < 256) {
    int rl = tid < mrem ? tid : 0;        // pad rows clamp to row 0 (valid addr)
    tokLds[tid] = slot_tok[slotBase + rl];
    gateLds[tid] = (tid < mrem) ? slot_gate[slotBase + rl] : 0.f;
  }
  __syncthreads();

  int wv = tid >> 6, lane = tid & 63;
  // staging chunks of 1KB = 16 rows x 64B(32 cols); 4 lanes/row, 16B each.
  // A: 16 chunks (2/wave); G,U: 8 chunks (1/wave). 4 gl2lds per thread per K-tile.
  const u16 *aSrc[2], *gSrc, *uSrc;
  int aOff[2], gOff;
  const u16* gBase = wgb + ((size_t)e * DINTER + iBase) * DMODEL;
  const u16* uBase = wub + ((size_t)e * DINTER + iBase) * DMODEL;
  int colOff = (lane & 3) * 8;
  int rl4 = lane >> 2;                 // row within chunk
#pragma unroll
  for (int i2 = 0; i2 < 2; ++i2) {
    int chunk = wv * 2 + i2;
    int row = chunk * 16 + rl4;
    aSrc[i2] = xb + (size_t)tokLds[row] * DMODEL + colOff;
    aOff[i2] = chunk * 512;
  }
  {
    int row = wv * 16 + rl4;
    gSrc = gBase + (size_t)row * DMODEL + colOff;
    uSrc = uBase + (size_t)row * DMODEL + colOff;
    gOff = wv * 512;
  }

  f32x4 accg[4][4] = {};
  f32x4 accu[4][4] = {};
  int fr = lane & 15, fq = lane >> 4;
  int wr = (wv >> 1) * 64, wc = (wv & 1) * 64;

  auto STAGE = [&](int buf, int kOff) {
#pragma unroll
    for (int i2 = 0; i2 < 2; ++i2) gl2lds16(aSrc[i2] + kOff, &sA[buf][aOff[i2]]);
    gl2lds16(gSrc + kOff, &sG[buf][gOff]);
    gl2lds16(uSrc + kOff, &sU[buf][gOff]);
  };
  auto COMPUTE = [&](int buf) {
    bf16x8 af[4], bg[4], bu[4];
#pragma unroll
    for (int mf = 0; mf < 4; ++mf)
      af[mf] = *(const bf16x8*)&sA[buf][(wr + mf * 16 + fr) * 32 + fq * 8];
#pragma unroll
    for (int nf = 0; nf < 4; ++nf) {
      bg[nf] = *(const bf16x8*)&sG[buf][(wc + nf * 16 + fr) * 32 + fq * 8];
      bu[nf] = *(const bf16x8*)&sU[buf][(wc + nf * 16 + fr) * 32 + fq * 8];
    }
    __builtin_amdgcn_s_setprio(1);
#pragma unroll
    for (int mf = 0; mf < 4; ++mf)
#pragma unroll
      for (int nf = 0; nf < 4; ++nf) {
        accg[mf][nf] = __builtin_amdgcn_mfma_f32_16x16x32_bf16(af[mf], bg[nf], accg[mf][nf], 0, 0, 0);
        accu[mf][nf] = __builtin_amdgcn_mfma_f32_16x16x32_bf16(af[mf], bu[nf], accu[mf][nf], 0, 0, 0);
      }
    __builtin_amdgcn_s_setprio(0);
  };

  const int NT = DMODEL / 32;  // 64
  STAGE(0, 0);
  STAGE(1, 32);
  VMCNT_BAR(4);                 // t0 landed; t1 in flight
#pragma unroll 1
  for (int t = 0; t < NT; ++t) {
    if (t + 2 < NT) {
      STAGE((t + 2) % 3, (t + 2) * 32);
      COMPUTE(t % 3);
      VMCNT_BAR(4);             // t+1 landed; t+2 (4 loads) may fly
    } else {
      COMPUTE(t % 3);
      if (t < NT - 1) VMCNT_BAR(0);
    }
  }

  // epilogue: act = silu(g)*u*gate -> bf16  (D layout: col=lane&15, row=(lane>>4)*4+r)
#pragma unroll
  for (int mf = 0; mf < 4; ++mf)
#pragma unroll
    for (int nf = 0; nf < 4; ++nf)
#pragma unroll
      for (int r = 0; r < 4; ++r) {
        int row = wr + mf * 16 + fq * 4 + r;
        if (row < mrem) {
          float g = accg[mf][nf][r], u = accu[mf][nf][r];
          float a = g / (1.f + __expf(-g)) * u * gateLds[row];
          act[(size_t)(slotBase + row) * DINTER + iBase + wc + nf * 16 + fr] = f2bf(a);
        }
      }
}

// GEMM2: y[tok, d] += act[slot,:] @ Wd[e,d,:]  (atomic scatter, <=6 adds/elem)
// 256x128 tile, BK=32, 8 waves, triple-buffered (3 loads/thread/K-tile -> vmcnt(3)).
__global__ __launch_bounds__(512, 2) void k_gemm2(
    const u16* __restrict__ act, const u16* __restrict__ wdb,
    const int* __restrict__ slot_tok, const int* __restrict__ offs,
    const int* __restrict__ counts, float* __restrict__ y) {
  // grid flat = 8(mt) x 16(dt) x 16(e) = 2048 = 8*256
  int b = blockIdx.x;
  int w = (b & 7) * 256 + (b >> 3);
  int mt = w & 7, rest = w >> 3;
  int dt = rest & 15, e = rest >> 4;

  int mcount = counts[e];
  if (mt * 256 >= mcount) return;
  int mrem = mcount - mt * 256; if (mrem > 256) mrem = 256;
  int slotBase = offs[e] + mt * 256;
  int dBase = dt * 128;

  __shared__ u16 sA[3][256 * 32];   // 16 KB per buffer
  __shared__ u16 sB[3][128 * 32];   // 8 KB per buffer -> 72 KB total
  __shared__ int tokLds[256];

  int tid = threadIdx.x;
  if (tid < 256) tokLds[tid] = slot_tok[slotBase + (tid < mrem ? tid : 0)];
  __syncthreads();

  int wv = tid >> 6, lane = tid & 63;
  const u16 *aSrc[2], *bSrc;
  int aOff[2], bOff;
  const u16* bBase = wdb + ((size_t)e * DMODEL + dBase) * DINTER;
  int colOff = (lane & 3) * 8;
  int rl4 = lane >> 2;
#pragma unroll
  for (int i2 = 0; i2 < 2; ++i2) {
    int chunk = wv * 2 + i2;
    int row = chunk * 16 + rl4;
    aSrc[i2] = act + (size_t)(slotBase + row) * DINTER + colOff;  // act padded +256 rows
    aOff[i2] = chunk * 512;
  }
  {
    int row = wv * 16 + rl4;
    bSrc = bBase + (size_t)row * DINTER + colOff;
    bOff = wv * 512;
  }

  f32x4 acc[4][4] = {};
  int fr = lane & 15, fq = lane >> 4;
  int wr = (wv >> 1) * 64, wc = (wv & 1) * 64;

  auto STAGE = [&](int buf, int kOff) {
#pragma unroll
    for (int i2 = 0; i2 < 2; ++i2) gl2lds16(aSrc[i2] + kOff, &sA[buf][aOff[i2]]);
    gl2lds16(bSrc + kOff, &sB[buf][bOff]);
  };
  auto COMPUTE = [&](int buf) {
    bf16x8 af[4], bb[4];
#pragma unroll
    for (int mf = 0; mf < 4; ++mf)
      af[mf] = *(const bf16x8*)&sA[buf][(wr + mf * 16 + fr) * 32 + fq * 8];
#pragma unroll
    for (int nf = 0; nf < 4; ++nf)
      bb[nf] = *(const bf16x8*)&sB[buf][(wc + nf * 16 + fr) * 32 + fq * 8];
    __builtin_amdgcn_s_setprio(1);
#pragma unroll
    for (int mf = 0; mf < 4; ++mf)
#pragma unroll
      for (int nf = 0; nf < 4; ++nf)
        acc[mf][nf] = __builtin_amdgcn_mfma_f32_16x16x32_bf16(af[mf], bb[nf], acc[mf][nf], 0, 0, 0);
    __builtin_amdgcn_s_setprio(0);
  };

  const int NT = DINTER / 32;  // 44
  STAGE(0, 0);
  STAGE(1, 32);
  VMCNT_BAR(3);
#pragma unroll 1
  for (int t = 0; t < NT; ++t) {
    if (t + 2 < NT) {
      STAGE((t + 2) % 3, (t + 2) * 32);
      COMPUTE(t % 3);
      VMCNT_BAR(3);
    } else {
      COMPUTE(t % 3);
      if (t < NT - 1) VMCNT_BAR(0);
    }
  }

#pragma unroll
  for (int mf = 0; mf < 4; ++mf)
#pragma unroll
    for (int nf = 0; nf < 4; ++nf)
#pragma unroll
      for (int r = 0; r < 4; ++r) {
        int row = wr + mf * 16 + fq * 4 + r;
        if (row < mrem) {
          int t = tokLds[row];
          atomicAdd(y + (size_t)t * DMODEL + dBase + wc + nf * 16 + fr, acc[mf][nf][r]);
        }
      }
}

extern "C" void kernel_launch(void* const* d_in, const int* in_sizes, int n_in,
                              void* d_out, int out_size, void* d_ws, size_t ws_size,
                              hipStream_t stream) {
  const float* x       = (const float*)d_in[0];
  const float* weights = (const float*)d_in[1];
  const int*   indices = (const int*)d_in[2];
  const float* Wg      = (const float*)d_in[3];
  const float* Wu      = (const float*)d_in[4];
  const float* Wd      = (const float*)d_in[5];
  float* y = (float*)d_out;

  const size_t WELEM = (size_t)NE * DINTER * DMODEL;  // 46.1M elems per weight tensor

  char* ws = (char*)d_ws;
  size_t o = 0;
  float* gate_w = (float*)(ws + o); o += (size_t)TT * NE * 4;       // 131072
  size_t ctrlOff = o;
  int* counts = (int*)(ws + o);
  int* offs   = (int*)(ws + o + 64);
  int* cursor = (int*)(ws + o + 192);
  o += 256;
  int*   slot_tok  = (int*)(ws + o);   o += (size_t)PMAX * 4;
  float* slot_gate = (float*)(ws + o); o += (size_t)PMAX * 4;
  u16* xb  = (u16*)(ws + o); o += (size_t)TT * DMODEL * 2;
  u16* act = (u16*)(ws + o); o += (size_t)(PMAX + 256) * DINTER * 2; // +256 pad rows
  u16* wgb = (u16*)(ws + o); o += WELEM * 2;
  u16* wub = (u16*)(ws + o); o += WELEM * 2;
  u16* wdb = (u16*)(ws + o); o += WELEM * 2;   // total ~306 MB
  (void)ws_size; (void)in_sizes; (void)n_in;

  hipMemsetAsync(d_out, 0, (size_t)out_size * 4, stream);
  hipMemsetAsync(ws + ctrlOff, 0, 256, stream);

  k_gate<<<TT * NE / 256, 256, 0, stream>>>(weights, indices, gate_w, counts);
  k_scan<<<1, 64, 0, stream>>>(counts, offs);
  k_fill<<<TT * NE / 256, 256, 0, stream>>>(gate_w, offs, cursor, slot_tok, slot_gate);
  k_castw<<<(TT * DMODEL / 8) / 256, 256, 0, stream>>>(x, xb, TT * DMODEL / 8);
  k_castw<<<2048, 256, 0, stream>>>(Wg, wgb, (int)(WELEM / 8));
  k_castw<<<2048, 256, 0, stream>>>(Wu, wub, (int)(WELEM / 8));
  k_castw<<<2048, 256, 0, stream>>>(Wd, wdb, (int)(WELEM / 8));
  k_gemm1<<<1408, 512, 0, stream>>>(xb, wgb, wub, slot_tok, slot_gate, offs, counts, act);
  k_gemm2<<<2048, 512, 0, stream>>>(act, wdb, slot_tok, offs, counts, y);
}

// Round 6
// 592.137 us; speedup vs baseline: 2.1492x; 2.1492x over previous
//
#include <hip/hip_runtime.h>
#include <hip/hip_bf16.h>
#include <cstdint>

// Problem constants (from reference)
#define TT     2048   // tokens
#define KSEL   6      // experts per token
#define DMODEL 2048   // model dim
#define DINTER 1408   // moe intermediate dim
#define NE     16     // routed experts
#define PMAX   (TT * KSEL)

typedef short bf16x8 __attribute__((ext_vector_type(8)));
typedef float f32x4 __attribute__((ext_vector_type(4)));
typedef unsigned short u16;
typedef u16 u16x8 __attribute__((ext_vector_type(8)));

__device__ __forceinline__ u16 f2bf(float f) {
  union { float f; unsigned u; } v; v.f = f;
  return (u16)((v.u + 0x7FFFu + ((v.u >> 16) & 1u)) >> 16);  // RNE
}

__device__ __forceinline__ void gl2lds16(const void* g, void* l) {
  __builtin_amdgcn_global_load_lds((const __attribute__((address_space(1))) void*)g,
                                   (__attribute__((address_space(3))) void*)l,
                                   16, 0, 0);
}

// gate_w[t,e] = sum_k weights[t,k]*(indices[t,k]==e); count routed (t,e) pairs
__global__ void k_gate(const float* __restrict__ w, const int* __restrict__ idx,
                       float* __restrict__ gate_w, int* __restrict__ counts) {
  int g = blockIdx.x * 256 + threadIdx.x;  // T*E threads
  int t = g >> 4, e = g & 15;
  const int* ip = idx + t * KSEL;
  const float* wp = w + t * KSEL;
  float s = 0.f;
#pragma unroll
  for (int k = 0; k < KSEL; ++k) s += (ip[k] == e) ? wp[k] : 0.f;
  gate_w[g] = s;
  if (s != 0.f) atomicAdd(counts + e, 1);
}

__global__ void k_scan(const int* __restrict__ counts, int* __restrict__ offs) {
  if (threadIdx.x == 0 && blockIdx.x == 0) {
    int r = 0;
#pragma unroll
    for (int e = 0; e < NE; ++e) { offs[e] = r; r += counts[e]; }
    offs[NE] = r;
  }
}

__global__ void k_fill(const float* __restrict__ gate_w, const int* __restrict__ offs,
                       int* __restrict__ cursor, int* __restrict__ slot_tok,
                       float* __restrict__ slot_gate) {
  int g = blockIdx.x * 256 + threadIdx.x;
  int t = g >> 4, e = g & 15;
  float s = gate_w[g];
  if (s != 0.f) {
    int p = atomicAdd(cursor + e, 1);
    int sl = offs[e] + p;
    slot_tok[sl] = t;
    slot_gate[sl] = s;
  }
}

// single merged fp32->bf16 cast over 4 tensors (x, Wg, Wu, Wd), 8 elems/thread
#define XV8   (TT * DMODEL / 8)                      // 524288
#define WV8   (NE * DINTER * DMODEL / 8)             // 5767168
__global__ void k_castall(const float* __restrict__ x,  u16* __restrict__ xb,
                          const float* __restrict__ wg, u16* __restrict__ wgb,
                          const float* __restrict__ wu, u16* __restrict__ wub,
                          const float* __restrict__ wd, u16* __restrict__ wdb) {
  const int total = XV8 + 3 * WV8;
  int stride = gridDim.x * 256;
  for (int i = blockIdx.x * 256 + threadIdx.x; i < total; i += stride) {
    const float* src; u16* dst; int j;
    if (i < XV8)                { src = x;  dst = xb;  j = i; }
    else if (i < XV8 + WV8)     { src = wg; dst = wgb; j = i - XV8; }
    else if (i < XV8 + 2 * WV8) { src = wu; dst = wub; j = i - XV8 - WV8; }
    else                        { src = wd; dst = wdb; j = i - XV8 - 2 * WV8; }
    const float4* p = (const float4*)src + (size_t)j * 2;
    float4 v0 = p[0], v1 = p[1];
    u16x8 o;
    o[0] = f2bf(v0.x); o[1] = f2bf(v0.y); o[2] = f2bf(v0.z); o[3] = f2bf(v0.w);
    o[4] = f2bf(v1.x); o[5] = f2bf(v1.y); o[6] = f2bf(v1.z); o[7] = f2bf(v1.w);
    *(u16x8*)(dst + (size_t)j * 8) = o;
  }
}

// ---------------------------------------------------------------------------
// LDS XOR swizzle (G4 / rule #21): LDS rows are 64 bf16 = 128 B = 8 16B-units.
// Write side: gl2lds dest linear; the GLOBAL source 16B-unit is pre-permuted
// u' = u ^ (row&7). Read side: ds_read unit cu' = cu ^ (row&7). Same involution
// both sides => correct data; fragment reads (16 rows, fixed cu) now spread
// across 8 bank-quads (2-way, free) instead of 16-way same-bank.
// ---------------------------------------------------------------------------

// GEMM1: act[slot, i] = silu(x@WgT)*(x@WuT)*gate, per expert token-group.
// R1 structure: 128x128 tile, BK=64, 4 waves (2Mx2N, 64x64, dual acc), 2-phase.
__global__ __launch_bounds__(256, 2) void k_gemm1(
    const u16* __restrict__ xb, const u16* __restrict__ wgb, const u16* __restrict__ wub,
    const int* __restrict__ slot_tok, const float* __restrict__ slot_gate,
    const int* __restrict__ offs, const int* __restrict__ counts,
    u16* __restrict__ act) {
  // XCD-chunked swizzle: grid flat = 16(mt) x 11(it) x 16(e) = 2816 = 8*352
  int b = blockIdx.x;
  int w = (b & 7) * 352 + (b >> 3);
  int mt = w & 15, rest = w >> 4;
  int it = rest % 11, e = rest / 11;

  int mcount = counts[e];
  if (mt * 128 >= mcount) return;
  int mrem = mcount - mt * 128; if (mrem > 128) mrem = 128;
  int slotBase = offs[e] + mt * 128;
  int iBase = it * 128;

  __shared__ u16 sA[128 * 64];
  __shared__ u16 sG[128 * 64];
  __shared__ u16 sU[128 * 64];
  __shared__ int tokLds[128];
  __shared__ float gateLds[128];

  int tid = threadIdx.x;
  if (tid < 128) {
    int rl = tid < mrem ? tid : 0;        // pad rows clamp to row 0 (valid addr)
    tokLds[tid] = slot_tok[slotBase + rl];
    gateLds[tid] = (tid < mrem) ? slot_gate[slotBase + rl] : 0.f;
  }
  __syncthreads();

  int wv = tid >> 6, lane = tid & 63;
  // staging: 16 chunks of 1KB (8 rows x 128B); wave wv owns chunks wv*4..wv*4+3
  // LDS dest = chunk base + lane*16 (linear, HW rule). Source unit swizzled:
  // row-in-chunk r8 = lane>>3 (= LDS row & 7), unit u' = (lane&7) ^ r8.
  const u16 *aSrc[4], *gSrc[4], *uSrc[4];
  u16 *aDst[4], *gDst[4], *uDst[4];
  const u16* gBase = wgb + ((size_t)e * DINTER + iBase) * DMODEL;
  const u16* uBase = wub + ((size_t)e * DINTER + iBase) * DMODEL;
  int r8 = lane >> 3;
  int colOff = (((lane & 7) ^ r8)) * 8;   // swizzled 16B-unit within the row
#pragma unroll
  for (int i2 = 0; i2 < 4; ++i2) {
    int chunk = wv * 4 + i2;
    int row = chunk * 8 + r8;
    aSrc[i2] = xb + (size_t)tokLds[row] * DMODEL + colOff;
    gSrc[i2] = gBase + (size_t)row * DMODEL + colOff;
    uSrc[i2] = uBase + (size_t)row * DMODEL + colOff;
    aDst[i2] = sA + chunk * 512;
    gDst[i2] = sG + chunk * 512;
    uDst[i2] = sU + chunk * 512;
  }

  f32x4 accg[4][4] = {};
  f32x4 accu[4][4] = {};
  int fr = lane & 15, fq = lane >> 4;
  int wr = (wv >> 1) * 64, wc = (wv & 1) * 64;

  for (int kb = 0; kb < DMODEL / 64; ++kb) {
    int kOff = kb * 64;
    __syncthreads();
#pragma unroll
    for (int i2 = 0; i2 < 4; ++i2) {
      gl2lds16(aSrc[i2] + kOff, aDst[i2]);
      gl2lds16(gSrc[i2] + kOff, gDst[i2]);
      gl2lds16(uSrc[i2] + kOff, uDst[i2]);
    }
    __syncthreads();
#pragma unroll
    for (int kf = 0; kf < 2; ++kf) {
      bf16x8 af[4], bg[4], bu[4];
#pragma unroll
      for (int mf = 0; mf < 4; ++mf) {
        int row = wr + mf * 16 + fr;
        int cu = ((kf * 4 + fq) ^ (row & 7)) * 8;
        af[mf] = *(const bf16x8*)&sA[row * 64 + cu];
      }
#pragma unroll
      for (int nf = 0; nf < 4; ++nf) {
        int row = wc + nf * 16 + fr;
        int cu = ((kf * 4 + fq) ^ (row & 7)) * 8;
        bg[nf] = *(const bf16x8*)&sG[row * 64 + cu];
        bu[nf] = *(const bf16x8*)&sU[row * 64 + cu];
      }
#pragma unroll
      for (int mf = 0; mf < 4; ++mf)
#pragma unroll
        for (int nf = 0; nf < 4; ++nf) {
          accg[mf][nf] = __builtin_amdgcn_mfma_f32_16x16x32_bf16(af[mf], bg[nf], accg[mf][nf], 0, 0, 0);
          accu[mf][nf] = __builtin_amdgcn_mfma_f32_16x16x32_bf16(af[mf], bu[nf], accu[mf][nf], 0, 0, 0);
        }
    }
  }
  // epilogue: act = silu(g)*u*gate -> bf16  (D layout: col=lane&15, row=(lane>>4)*4+r)
#pragma unroll
  for (int mf = 0; mf < 4; ++mf)
#pragma unroll
    for (int nf = 0; nf < 4; ++nf)
#pragma unroll
      for (int r = 0; r < 4; ++r) {
        int row = wr + mf * 16 + fq * 4 + r;
        if (row < mrem) {
          float g = accg[mf][nf][r], u = accu[mf][nf][r];
          float a = g / (1.f + __expf(-g)) * u * gateLds[row];
          act[(size_t)(slotBase + row) * DINTER + iBase + wc + nf * 16 + fr] = f2bf(a);
        }
      }
}

// GEMM2: y[tok, d] += act[slot,:] @ Wd[e,d,:]  (atomic scatter, <=6 adds/elem)
__global__ __launch_bounds__(256, 4) void k_gemm2(
    const u16* __restrict__ act, const u16* __restrict__ wdb,
    const int* __restrict__ slot_tok, const int* __restrict__ offs,
    const int* __restrict__ counts, float* __restrict__ y) {
  // grid flat = 16(mt) x 16(dt) x 16(e) = 4096 = 8*512
  int b = blockIdx.x;
  int w = (b & 7) * 512 + (b >> 3);
  int mt = w & 15, rest = w >> 4;
  int dt = rest & 15, e = rest >> 4;

  int mcount = counts[e];
  if (mt * 128 >= mcount) return;
  int mrem = mcount - mt * 128; if (mrem > 128) mrem = 128;
  int slotBase = offs[e] + mt * 128;
  int dBase = dt * 128;

  __shared__ u16 sA[128 * 64];
  __shared__ u16 sB[128 * 64];
  __shared__ int tokLds[128];

  int tid = threadIdx.x;
  if (tid < 128) tokLds[tid] = slot_tok[slotBase + (tid < mrem ? tid : 0)];
  __syncthreads();

  int wv = tid >> 6, lane = tid & 63;
  const u16 *aSrc[4], *bSrc[4];
  u16 *aDst[4], *bDst[4];
  const u16* bBase = wdb + ((size_t)e * DMODEL + dBase) * DINTER;
  int r8 = lane >> 3;
  int colOff = (((lane & 7) ^ r8)) * 8;   // swizzled 16B-unit
#pragma unroll
  for (int i2 = 0; i2 < 4; ++i2) {
    int chunk = wv * 4 + i2;
    int row = chunk * 8 + r8;
    aSrc[i2] = act + (size_t)(slotBase + row) * DINTER + colOff;  // act padded +128 rows
    bSrc[i2] = bBase + (size_t)row * DINTER + colOff;
    aDst[i2] = sA + chunk * 512;
    bDst[i2] = sB + chunk * 512;
  }

  f32x4 acc[4][4] = {};
  int fr = lane & 15, fq = lane >> 4;
  int wr = (wv >> 1) * 64, wc = (wv & 1) * 64;

  for (int kb = 0; kb < DINTER / 64; ++kb) {
    int kOff = kb * 64;
    __syncthreads();
#pragma unroll
    for (int i2 = 0; i2 < 4; ++i2) {
      gl2lds16(aSrc[i2] + kOff, aDst[i2]);
      gl2lds16(bSrc[i2] + kOff, bDst[i2]);
    }
    __syncthreads();
#pragma unroll
    for (int kf = 0; kf < 2; ++kf) {
      bf16x8 af[4], bb[4];
#pragma unroll
      for (int mf = 0; mf < 4; ++mf) {
        int row = wr + mf * 16 + fr;
        int cu = ((kf * 4 + fq) ^ (row & 7)) * 8;
        af[mf] = *(const bf16x8*)&sA[row * 64 + cu];
      }
#pragma unroll
      for (int nf = 0; nf < 4; ++nf) {
        int row = wc + nf * 16 + fr;
        int cu = ((kf * 4 + fq) ^ (row & 7)) * 8;
        bb[nf] = *(const bf16x8*)&sB[row * 64 + cu];
      }
#pragma unroll
      for (int mf = 0; mf < 4; ++mf)
#pragma unroll
        for (int nf = 0; nf < 4; ++nf)
          acc[mf][nf] = __builtin_amdgcn_mfma_f32_16x16x32_bf16(af[mf], bb[nf], acc[mf][nf], 0, 0, 0);
    }
  }
#pragma unroll
  for (int mf = 0; mf < 4; ++mf)
#pragma unroll
    for (int nf = 0; nf < 4; ++nf)
#pragma unroll
      for (int r = 0; r < 4; ++r) {
        int row = wr + mf * 16 + fq * 4 + r;
        if (row < mrem) {
          int t = tokLds[row];
          atomicAdd(y + (size_t)t * DMODEL + dBase + wc + nf * 16 + fr, acc[mf][nf][r]);
        }
      }
}

extern "C" void kernel_launch(void* const* d_in, const int* in_sizes, int n_in,
                              void* d_out, int out_size, void* d_ws, size_t ws_size,
                              hipStream_t stream) {
  const float* x       = (const float*)d_in[0];
  const float* weights = (const float*)d_in[1];
  const int*   indices = (const int*)d_in[2];
  const float* Wg      = (const float*)d_in[3];
  const float* Wu      = (const float*)d_in[4];
  const float* Wd      = (const float*)d_in[5];
  float* y = (float*)d_out;

  const size_t WELEM = (size_t)NE * DINTER * DMODEL;  // 46.1M elems per weight tensor

  char* ws = (char*)d_ws;
  size_t o = 0;
  float* gate_w = (float*)(ws + o); o += (size_t)TT * NE * 4;       // 131072
  size_t ctrlOff = o;
  int* counts = (int*)(ws + o);
  int* offs   = (int*)(ws + o + 64);
  int* cursor = (int*)(ws + o + 192);
  o += 256;
  int*   slot_tok  = (int*)(ws + o);   o += (size_t)PMAX * 4;
  float* slot_gate = (float*)(ws + o); o += (size_t)PMAX * 4;
  u16* xb  = (u16*)(ws + o); o += (size_t)TT * DMODEL * 2;
  u16* act = (u16*)(ws + o); o += (size_t)(PMAX + 128) * DINTER * 2; // +128 pad rows
  u16* wgb = (u16*)(ws + o); o += WELEM * 2;
  u16* wub = (u16*)(ws + o); o += WELEM * 2;
  u16* wdb = (u16*)(ws + o); o += WELEM * 2;   // total ~306 MB
  (void)ws_size; (void)in_sizes; (void)n_in;

  hipMemsetAsync(d_out, 0, (size_t)out_size * 4, stream);
  hipMemsetAsync(ws + ctrlOff, 0, 256, stream);

  k_gate<<<TT * NE / 256, 256, 0, stream>>>(weights, indices, gate_w, counts);
  k_scan<<<1, 64, 0, stream>>>(counts, offs);
  k_fill<<<TT * NE / 256, 256, 0, stream>>>(gate_w, offs, cursor, slot_tok, slot_gate);
  k_castall<<<2048, 256, 0, stream>>>(x, xb, Wg, wgb, Wu, wub, Wd, wdb);
  k_gemm1<<<2816, 256, 0, stream>>>(xb, wgb, wub, slot_tok, slot_gate, offs, counts, act);
  k_gemm2<<<4096, 256, 0, stream>>>(act, wdb, slot_tok, offs, counts, y);
}